// Round 5
// baseline (622.821 us; speedup 1.0000x reference)
//
#include <hip/hip_runtime.h>
#include <float.h>

#define NN 50000
#define NE 800000
#define NG 64
#define CAP 64

typedef __attribute__((ext_vector_type(8))) short bf16x8;
typedef __attribute__((ext_vector_type(4))) float f32x4;
typedef __attribute__((ext_vector_type(4))) _Float16 half4;
typedef __attribute__((ext_vector_type(2))) _Float16 half2v;

// ---------- helpers ----------
__device__ __forceinline__ unsigned f2mono(float f) {
  unsigned b = __float_as_uint(f);
  return (b & 0x80000000u) ? ~b : (b | 0x80000000u);
}
__device__ __forceinline__ float mono2f(unsigned u) {
  unsigned b = (u & 0x80000000u) ? (u & 0x7fffffffu) : ~u;
  return __uint_as_float(b);
}
__device__ __forceinline__ unsigned short bf16rn(float f) {
  unsigned u = __float_as_uint(f);
  unsigned r = u + 0x7FFFu + ((u >> 16) & 1u);
  return (unsigned short)(r >> 16);
}
__device__ __forceinline__ float bf2f(unsigned short h) {
  return __uint_as_float(((unsigned)h) << 16);
}
__device__ __forceinline__ void split2(float a, unsigned short* hi, unsigned short* lo) {
  unsigned short h = bf16rn(a);
  *hi = h;
  *lo = bf16rn(a - bf2f(h));
}

// ---------- degree count + ELL adjacency fill (by dst) ----------
__global__ void k_count(const int* __restrict__ src, const int* __restrict__ dst,
                        int* __restrict__ cnt, int* __restrict__ col) {
  int e = blockIdx.x * blockDim.x + threadIdx.x;
  if (e >= NE) return;
  int d = dst[e];
  int s = src[e];
  if ((unsigned)d >= NN || (unsigned)s >= NN) return;
  int pos = atomicAdd(&cnt[d], 1);
  if (pos < CAP) col[d * CAP + pos] = s;
}

// dinv + pre-scaled input features xs = x * dinv[v]
__global__ void k_dinv(const int* __restrict__ cnt, float* __restrict__ dinv,
                       const float* __restrict__ x, float* __restrict__ xs) {
  int v = blockIdx.x * blockDim.x + threadIdx.x;
  if (v >= NN) return;
  float d = rsqrtf((float)cnt[v] + 1.0f);
  dinv[v] = d;
#pragma unroll
  for (int i = 0; i < 9; ++i) xs[v * 9 + i] = x[v * 9 + i] * d;
}

// ---------- weight split+transpose, hi/lo interleaved per-8: out[n][k8][{hi8,lo8}] ----------
__global__ void k_splitw(const float* __restrict__ W, unsigned short* __restrict__ Wi,
                         int K, int Nc) {
  int i = blockIdx.x * blockDim.x + threadIdx.x;
  if (i >= K * Nc) return;
  int k = i / Nc, n = i - k * Nc;
  float w = W[i];
  unsigned short h, l;
  split2(w, &h, &l);
  size_t base = (size_t)n * 2 * K + (size_t)(k >> 3) * 16 + (k & 7);
  Wi[base] = h;
  Wi[base + 8] = l;
}

// ---------- aggregation F=9: 16-lane group per node ----------
__global__ __launch_bounds__(256) void k_agg9(const float* __restrict__ xs,
                                              float* __restrict__ out,
                                              const int* __restrict__ cnt,
                                              const int* __restrict__ col,
                                              const float* __restrict__ dinv) {
  int v = (blockIdx.x * 256 + threadIdx.x) >> 4;
  int l = threadIdx.x & 15;
  if (v >= NN) return;
  int c = cnt[v]; if (c > CAP) c = CAP;
  const int* cl = col + v * CAP;
  float acc = (l < 9) ? xs[v * 9 + l] : 0.0f;
  int j = 0;
  for (; j + 4 <= c; j += 4) {
    int4 u = *(const int4*)(cl + j);
    float a0 = (l < 9) ? xs[u.x * 9 + l] : 0.f;
    float a1 = (l < 9) ? xs[u.y * 9 + l] : 0.f;
    float a2 = (l < 9) ? xs[u.z * 9 + l] : 0.f;
    float a3 = (l < 9) ? xs[u.w * 9 + l] : 0.f;
    acc += (a0 + a1) + (a2 + a3);
  }
  for (; j < c; ++j) {
    int u = cl[j];
    if (l < 9) acc += xs[u * 9 + l];
  }
  if (l < 9) out[v * 9 + l] = acc * dinv[v];
}

// ---------- GEMM K=9 -> 128, + bias + relu; writes fp16 (pre-scaled by dinv) ----------
__global__ __launch_bounds__(256) void k_gemm9(const float* __restrict__ in,
                                               const float* __restrict__ W,
                                               const float* __restrict__ bias,
                                               const float* __restrict__ dinv,
                                               _Float16* __restrict__ out) {
  __shared__ float sW[9 * 128];
  __shared__ float sb[128];
  int t = threadIdx.x;
  if (t < 128) sb[t] = bias[t];
  for (int i = t; i < 9 * 128; i += 256) sW[i] = W[i];
  __syncthreads();
  int r = blockIdx.x * 2 + (t >> 7);
  int c = t & 127;
  if (r >= NN) return;
  float acc = sb[c];
#pragma unroll
  for (int i = 0; i < 9; ++i) acc += in[r * 9 + i] * sW[i * 128 + c];
  out[r * 128 + c] = (_Float16)(fmaxf(acc, 0.0f) * dinv[r]);
}

// ---------- aggregation F=128 (wave/node), fp16 gather, emits interleaved split bf16 ----------
// A layout: [row][k8(16)][{hi8,lo8}]  (256 ushorts per row)
__global__ __launch_bounds__(256) void k_agg128(const half2v* __restrict__ h,
                                                unsigned short* __restrict__ Ai,
                                                const int* __restrict__ cnt,
                                                const int* __restrict__ col,
                                                const float* __restrict__ dinv) {
  int w = (blockIdx.x * 256 + threadIdx.x) >> 6;
  int lane = threadIdx.x & 63;
  if (w >= NN) return;
  half2v s = h[(size_t)w * 64 + lane];
  float ax = (float)s.x, ay = (float)s.y;
  int c = cnt[w]; if (c > CAP) c = CAP;
  const int* cl = col + w * CAP;
  int j = 0;
  for (; j + 4 <= c; j += 4) {
    int4 u = *(const int4*)(cl + j);
    half2v t0 = h[(size_t)u.x * 64 + lane];
    half2v t1 = h[(size_t)u.y * 64 + lane];
    half2v t2 = h[(size_t)u.z * 64 + lane];
    half2v t3 = h[(size_t)u.w * 64 + lane];
    ax += ((float)t0.x + (float)t1.x) + ((float)t2.x + (float)t3.x);
    ay += ((float)t0.y + (float)t1.y) + ((float)t2.y + (float)t3.y);
  }
  for (; j < c; ++j) {
    int u = cl[j];
    half2v tv = h[(size_t)u * 64 + lane];
    ax += (float)tv.x; ay += (float)tv.y;
  }
  float di = dinv[w];
  ax *= di; ay *= di;
  ushort2 hv, lv;
  split2(ax, &hv.x, &lv.x);
  split2(ay, &hv.y, &lv.y);
  // k = 2*lane..2*lane+1 -> k8 = lane>>2, j0 = 2*(lane&3)
  size_t base = (size_t)w * 256 + (size_t)(lane >> 2) * 16 + 2 * (lane & 3);
  *(ushort2*)(Ai + base) = hv;
  *(ushort2*)(Ai + base + 8) = lv;
}

// ---------- aggregation F=256 (wave/node), fp16 gather, emits interleaved split bf16 ----------
// A layout: [row][k8(32)][{hi8,lo8}]  (512 ushorts per row)
__global__ __launch_bounds__(256) void k_agg256(const half4* __restrict__ h,
                                                unsigned short* __restrict__ Ai,
                                                const int* __restrict__ cnt,
                                                const int* __restrict__ col,
                                                const float* __restrict__ dinv) {
  int w = (blockIdx.x * 256 + threadIdx.x) >> 6;
  int lane = threadIdx.x & 63;
  if (w >= NN) return;
  half4 s = h[(size_t)w * 64 + lane];
  float ax = (float)s.x, ay = (float)s.y, az = (float)s.z, aw = (float)s.w;
  int c = cnt[w]; if (c > CAP) c = CAP;
  const int* cl = col + w * CAP;
  int j = 0;
  for (; j + 4 <= c; j += 4) {
    int4 u = *(const int4*)(cl + j);
    half4 t0 = h[(size_t)u.x * 64 + lane];
    half4 t1 = h[(size_t)u.y * 64 + lane];
    half4 t2 = h[(size_t)u.z * 64 + lane];
    half4 t3 = h[(size_t)u.w * 64 + lane];
    ax += ((float)t0.x + (float)t1.x) + ((float)t2.x + (float)t3.x);
    ay += ((float)t0.y + (float)t1.y) + ((float)t2.y + (float)t3.y);
    az += ((float)t0.z + (float)t1.z) + ((float)t2.z + (float)t3.z);
    aw += ((float)t0.w + (float)t1.w) + ((float)t2.w + (float)t3.w);
  }
  for (; j < c; ++j) {
    int u = cl[j];
    half4 tv = h[(size_t)u * 64 + lane];
    ax += (float)tv.x; ay += (float)tv.y; az += (float)tv.z; aw += (float)tv.w;
  }
  float di = dinv[w];
  ax *= di; ay *= di; az *= di; aw *= di;
  ushort4 hv, lv;
  split2(ax, &hv.x, &lv.x);
  split2(ay, &hv.y, &lv.y);
  split2(az, &hv.z, &lv.z);
  split2(aw, &hv.w, &lv.w);
  // k = 4*lane..4*lane+3 -> k8 = lane>>1, j0 = 4*(lane&1)
  size_t base = (size_t)w * 512 + (size_t)(lane >> 1) * 16 + 4 * (lane & 1);
  *(ushort4*)(Ai + base) = hv;
  *(ushort4*)(Ai + base + 8) = lv;
}

// ---------- LDS-staged pipelined MFMA bf16x3-split GEMM ----------
// A: [M][K/8][{hi8,lo8}] interleaved; B: [Nc][K/8][{hi8,lo8}] interleaved.
// block 128x128 (4 waves 2x2, 64x64/wave). K-step 32 (= 4 k8-blocks = 128B/row).
// LDS rows padded: 72 ushorts (144B) per row -> <=2-way bank aliasing (free).
// mode 1: C(fp16) = relu(acc+bias)*dinv[row]; mode 2: fused max-pool, no C write.
#define LROW 72
__global__ __launch_bounds__(256) void k_mm(const unsigned short* __restrict__ A,
                                            const unsigned short* __restrict__ B,
                                            const float* __restrict__ bias,
                                            _Float16* __restrict__ C,
                                            const float* __restrict__ dinv,
                                            const int* __restrict__ batch,
                                            unsigned* __restrict__ gpool,
                                            int M, int K, int Nc, int mode) {
  __shared__ __align__(16) unsigned short Al[128 * LROW];
  __shared__ __align__(16) unsigned short Bl[128 * LROW];
  int t = threadIdx.x;
  int wave = t >> 6, lane = t & 63;
  int wm = wave & 1, wn = wave >> 1;
  int rowBase = blockIdx.x * 128;
  int colBase = blockIdx.y * 128;
  int lm = lane & 15;
  int q  = lane >> 4;              // k8 index within the 32-k step
  int srow = t >> 3;               // staging: rows srow+32c, 16B-seg sseg
  int sseg = t & 7;
  size_t K2 = 2 * (size_t)K;       // ushorts per row (hi+lo)

  f32x4 acc[4][4];
#pragma unroll
  for (int i = 0; i < 4; ++i)
#pragma unroll
    for (int j = 0; j < 4; ++j) acc[i][j] = (f32x4){0.f, 0.f, 0.f, 0.f};

  float4 pa[4], pb[4];
  auto prefetch = [&](int s) {
#pragma unroll
    for (int c = 0; c < 4; ++c) {
      int row = srow + 32 * c;
      int ga = rowBase + row; if (ga > M - 1) ga = M - 1;   // clamp tail rows
      pa[c] = *(const float4*)(A + (size_t)ga * K2 + (size_t)s * 64 + sseg * 8);
      pb[c] = *(const float4*)(B + (size_t)(colBase + row) * K2 + (size_t)s * 64 + sseg * 8);
    }
  };

  int nsteps = K >> 5;
  prefetch(0);
  for (int s = 0; s < nsteps; ++s) {
    __syncthreads();               // previous step's ds_reads complete
#pragma unroll
    for (int c = 0; c < 4; ++c) {
      int row = srow + 32 * c;
      *(float4*)(Al + row * LROW + sseg * 8) = pa[c];
      *(float4*)(Bl + row * LROW + sseg * 8) = pb[c];
    }
    if (s + 1 < nsteps) prefetch(s + 1);   // loads fly during this step's MFMAs
    __syncthreads();

    bf16x8 bh[4], blo[4];
#pragma unroll
    for (int ni = 0; ni < 4; ++ni) {
      const unsigned short* p = Bl + (wn * 64 + ni * 16 + lm) * LROW + q * 16;
      bh[ni]  = *(const bf16x8*)p;
      blo[ni] = *(const bf16x8*)(p + 8);
    }
#pragma unroll
    for (int mi = 0; mi < 4; ++mi) {
      const unsigned short* p = Al + (wm * 64 + mi * 16 + lm) * LROW + q * 16;
      bf16x8 ah = *(const bf16x8*)p;
      bf16x8 al = *(const bf16x8*)(p + 8);
#pragma unroll
      for (int ni = 0; ni < 4; ++ni) {
        acc[mi][ni] = __builtin_amdgcn_mfma_f32_16x16x32_bf16(ah, bh[ni],  acc[mi][ni], 0, 0, 0);
        acc[mi][ni] = __builtin_amdgcn_mfma_f32_16x16x32_bf16(ah, blo[ni], acc[mi][ni], 0, 0, 0);
        acc[mi][ni] = __builtin_amdgcn_mfma_f32_16x16x32_bf16(al, bh[ni],  acc[mi][ni], 0, 0, 0);
      }
    }
  }

  // C/D layout: col = lane&15, row = (lane>>4)*4 + reg
  int rowOff = (lane >> 4) * 4;
  if (mode == 2) {
    __syncthreads();                       // staging buffers now dead -> reuse as pool
    unsigned* ldsPool = (unsigned*)Al;
    for (int i = t; i < 4 * 256; i += 256) ldsPool[i] = 0u;
    __syncthreads();
    int b0 = batch[rowBase];
#pragma unroll
    for (int mi = 0; mi < 4; ++mi) {
#pragma unroll
      for (int ni = 0; ni < 4; ++ni) {
        int gc = colBase + wn * 64 + ni * 16 + lm;
        float bsv = bias[gc];
#pragma unroll
        for (int r = 0; r < 4; ++r) {
          int gr = rowBase + wm * 64 + mi * 16 + rowOff + r;
          if (gr < M) {
            float v = acc[mi][ni][r] + bsv;
            int idx = batch[gr] - b0;
            if (idx < 0) idx = 0;
            if (idx > 3) idx = 3;
            atomicMax(&ldsPool[idx * 256 + gc], f2mono(v));
          }
        }
      }
    }
    __syncthreads();
#pragma unroll
    for (int s4 = 0; s4 < 4; ++s4) {
      unsigned mv = ldsPool[s4 * 256 + t];
      int gb = b0 + s4;
      if (mv && gb < NG) atomicMax(&gpool[gb * 256 + t], mv);
    }
  } else {
#pragma unroll
    for (int mi = 0; mi < 4; ++mi) {
#pragma unroll
      for (int ni = 0; ni < 4; ++ni) {
        int gc = colBase + wn * 64 + ni * 16 + lm;
        float bsv = bias[gc];
#pragma unroll
        for (int r = 0; r < 4; ++r) {
          int gr = rowBase + wm * 64 + mi * 16 + rowOff + r;
          if (gr < M) {
            float v = fmaxf(acc[mi][ni][r] + bsv, 0.0f);
            C[(size_t)gr * Nc + gc] = (_Float16)(v * dinv[gr]);
          }
        }
      }
    }
  }
}

// ---------- dense head ----------
__global__ __launch_bounds__(256) void k_head(const unsigned* __restrict__ g,
                                              const float* __restrict__ Wl2, const float* __restrict__ bl2,
                                              const float* __restrict__ Wl3, const float* __restrict__ bl3,
                                              const float* __restrict__ Wl, const float* __restrict__ bl,
                                              float* __restrict__ out) {
  __shared__ float s0[256];
  __shared__ float s1[128];
  __shared__ float s2[128];
  int b = blockIdx.x, t = threadIdx.x;
  s0[t] = mono2f(g[b * 256 + t]);
  __syncthreads();
  if (t < 128) {
    float acc = bl2[t];
    for (int k = 0; k < 256; ++k) acc += s0[k] * Wl2[k * 128 + t];
    s1[t] = fmaxf(acc, 0.0f);
  }
  __syncthreads();
  if (t < 128) {
    float acc = bl3[t];
    for (int k = 0; k < 128; ++k) acc += s1[k] * Wl3[k * 128 + t];
    s2[t] = fmaxf(acc, 0.0f);
  }
  __syncthreads();
  if (t < 10) {
    float acc = bl[t];
    for (int k = 0; k < 128; ++k) acc += s2[k] * Wl[k * 10 + t];
    out[b * 10 + t] = acc;
  }
}

extern "C" void kernel_launch(void* const* d_in, const int* in_sizes, int n_in,
                              void* d_out, int out_size, void* d_ws, size_t ws_size,
                              hipStream_t stream) {
  const float* x   = (const float*)d_in[0];
  const int* eidx  = (const int*)d_in[1];
  const int* batch = (const int*)d_in[2];
  const float* W1 = (const float*)d_in[3];   const float* b1 = (const float*)d_in[4];
  const float* W2 = (const float*)d_in[5];   const float* b2 = (const float*)d_in[6];
  const float* W3 = (const float*)d_in[7];   const float* b3 = (const float*)d_in[8];
  const float* W4 = (const float*)d_in[9];   const float* b4 = (const float*)d_in[10];
  const float* Wl2 = (const float*)d_in[11]; const float* bl2 = (const float*)d_in[12];
  const float* Wl3 = (const float*)d_in[13]; const float* bl3 = (const float*)d_in[14];
  const float* Wl  = (const float*)d_in[15]; const float* bl  = (const float*)d_in[16];
  float* out = (float*)d_out;

  // ---- workspace carve ----
  _Float16* hs = (_Float16*)d_ws;                                  // NN*256 fp16
  unsigned short* Ai = (unsigned short*)(hs + (size_t)NN * 256);   // NN*512 ushort (interleaved hi/lo)
  int* cnt  = (int*)(Ai + (size_t)NN * 512);                       // NN
  float* dinv = (float*)(cnt + NN);                                // NN
  int* col  = (int*)(dinv + NN);                                   // NN*CAP
  unsigned* g = (unsigned*)(col + (size_t)NN * CAP);               // NG*256
  unsigned short* W2i = (unsigned short*)(g + NG * 256);           // 256*256
  unsigned short* W3i = W2i + 256 * 256;                           // 256*512
  unsigned short* W4i = W3i + 256 * 512;                           // 256*512
  float* xs = (float*)hs;        // NN*9 fp32, dead before k_gemm9 writes hs
  float* agg9out = (float*)Ai;   // NN*9 fp32, dead before k_agg128 writes Ai

  const int* src = eidx;
  const int* dst = eidx + NE;

  hipMemsetAsync(cnt, 0, NN * sizeof(int), stream);
  hipMemsetAsync(g, 0, NG * 256 * sizeof(unsigned), stream);

  k_count<<<(NE + 255) / 256, 256, 0, stream>>>(src, dst, cnt, col);
  k_dinv<<<(NN + 255) / 256, 256, 0, stream>>>(cnt, dinv, x, xs);

  k_splitw<<<(128 * 256 + 255) / 256, 256, 0, stream>>>(W2, W2i, 128, 256);
  k_splitw<<<(256 * 256 + 255) / 256, 256, 0, stream>>>(W3, W3i, 256, 256);
  k_splitw<<<(256 * 256 + 255) / 256, 256, 0, stream>>>(W4, W4i, 256, 256);

  // layer 1: agg 9-dim fp32, GEMM 9->128 (+relu, *dinv, fp16 out)
  k_agg9<<<(NN + 15) / 16, 256, 0, stream>>>(xs, agg9out, cnt, col, dinv);
  k_gemm9<<<NN / 2, 256, 0, stream>>>(agg9out, W1, b1, dinv, hs);

  dim3 gmm((NN + 127) / 128, 2);

  // layer 2: fp16 gather 128-dim, LDS-staged MFMA GEMM 128->256
  k_agg128<<<(NN + 3) / 4, 256, 0, stream>>>((const half2v*)hs, Ai, cnt, col, dinv);
  k_mm<<<gmm, 256, 0, stream>>>(Ai, W2i, b2, hs, dinv, batch, g, NN, 128, 256, 1);

  // layer 3: fp16 gather 256-dim
  k_agg256<<<(NN + 3) / 4, 256, 0, stream>>>((const half4*)hs, Ai, cnt, col, dinv);
  k_mm<<<gmm, 256, 0, stream>>>(Ai, W3i, b3, hs, dinv, batch, g, NN, 256, 256, 1);

  // layer 4: fp16 gather 256-dim, GEMM + fused max-pool (no C write)
  k_agg256<<<(NN + 3) / 4, 256, 0, stream>>>((const half4*)hs, Ai, cnt, col, dinv);
  k_mm<<<gmm, 256, 0, stream>>>(Ai, W4i, b4, hs, dinv, batch, g, NN, 256, 256, 2);

  // head
  k_head<<<NG, 256, 0, stream>>>(g, Wl2, bl2, Wl3, bl3, Wl, bl, out);
}

// Round 6
// 575.066 us; speedup vs baseline: 1.0830x; 1.0830x over previous
//
#include <hip/hip_runtime.h>
#include <float.h>

#define NN 50000
#define NE 800000
#define NG 64
#define CAP 64

typedef __attribute__((ext_vector_type(8))) short bf16x8;
typedef __attribute__((ext_vector_type(4))) float f32x4;
typedef __attribute__((ext_vector_type(4))) _Float16 half4;
typedef __attribute__((ext_vector_type(2))) _Float16 half2v;

// ---------- helpers ----------
__device__ __forceinline__ unsigned f2mono(float f) {
  unsigned b = __float_as_uint(f);
  return (b & 0x80000000u) ? ~b : (b | 0x80000000u);
}
__device__ __forceinline__ float mono2f(unsigned u) {
  unsigned b = (u & 0x80000000u) ? (u & 0x7fffffffu) : ~u;
  return __uint_as_float(b);
}
__device__ __forceinline__ unsigned short bf16rn(float f) {
  unsigned u = __float_as_uint(f);
  unsigned r = u + 0x7FFFu + ((u >> 16) & 1u);
  return (unsigned short)(r >> 16);
}
__device__ __forceinline__ float bf2f(unsigned short h) {
  return __uint_as_float(((unsigned)h) << 16);
}
__device__ __forceinline__ void split2(float a, unsigned short* hi, unsigned short* lo) {
  unsigned short h = bf16rn(a);
  *hi = h;
  *lo = bf16rn(a - bf2f(h));
}

// ---------- degree count + ELL adjacency fill (by dst) ----------
__global__ void k_count(const int* __restrict__ src, const int* __restrict__ dst,
                        int* __restrict__ cnt, int* __restrict__ col) {
  int e = blockIdx.x * blockDim.x + threadIdx.x;
  if (e >= NE) return;
  int d = dst[e];
  int s = src[e];
  if ((unsigned)d >= NN || (unsigned)s >= NN) return;
  int pos = atomicAdd(&cnt[d], 1);
  if (pos < CAP) col[d * CAP + pos] = s;
}

// dinv + pre-scaled input features xs = x * dinv[v]
__global__ void k_dinv(const int* __restrict__ cnt, float* __restrict__ dinv,
                       const float* __restrict__ x, float* __restrict__ xs) {
  int v = blockIdx.x * blockDim.x + threadIdx.x;
  if (v >= NN) return;
  float d = rsqrtf((float)cnt[v] + 1.0f);
  dinv[v] = d;
#pragma unroll
  for (int i = 0; i < 9; ++i) xs[v * 9 + i] = x[v * 9 + i] * d;
}

// ---------- weight split+transpose, hi/lo interleaved per-8: out[n][k8][{hi8,lo8}] ----------
__global__ void k_splitw(const float* __restrict__ W, unsigned short* __restrict__ Wi,
                         int K, int Nc) {
  int i = blockIdx.x * blockDim.x + threadIdx.x;
  if (i >= K * Nc) return;
  int k = i / Nc, n = i - k * Nc;
  float w = W[i];
  unsigned short h, l;
  split2(w, &h, &l);
  size_t base = (size_t)n * 2 * K + (size_t)(k >> 3) * 16 + (k & 7);
  Wi[base] = h;
  Wi[base + 8] = l;
}

// ---------- aggregation F=9: 16-lane group per node ----------
__global__ __launch_bounds__(256) void k_agg9(const float* __restrict__ xs,
                                              float* __restrict__ out,
                                              const int* __restrict__ cnt,
                                              const int* __restrict__ col,
                                              const float* __restrict__ dinv) {
  int v = (blockIdx.x * 256 + threadIdx.x) >> 4;
  int l = threadIdx.x & 15;
  if (v >= NN) return;
  int c = cnt[v]; if (c > CAP) c = CAP;
  const int* cl = col + v * CAP;
  float acc = (l < 9) ? xs[v * 9 + l] : 0.0f;
  int j = 0;
  for (; j + 4 <= c; j += 4) {
    int4 u = *(const int4*)(cl + j);
    float a0 = (l < 9) ? xs[u.x * 9 + l] : 0.f;
    float a1 = (l < 9) ? xs[u.y * 9 + l] : 0.f;
    float a2 = (l < 9) ? xs[u.z * 9 + l] : 0.f;
    float a3 = (l < 9) ? xs[u.w * 9 + l] : 0.f;
    acc += (a0 + a1) + (a2 + a3);
  }
  for (; j < c; ++j) {
    int u = cl[j];
    if (l < 9) acc += xs[u * 9 + l];
  }
  if (l < 9) out[v * 9 + l] = acc * dinv[v];
}

// ---------- GEMM K=9 -> 128, + bias + relu; writes fp16 (pre-scaled by dinv) ----------
__global__ __launch_bounds__(256) void k_gemm9(const float* __restrict__ in,
                                               const float* __restrict__ W,
                                               const float* __restrict__ bias,
                                               const float* __restrict__ dinv,
                                               _Float16* __restrict__ out) {
  __shared__ float sW[9 * 128];
  __shared__ float sb[128];
  int t = threadIdx.x;
  if (t < 128) sb[t] = bias[t];
  for (int i = t; i < 9 * 128; i += 256) sW[i] = W[i];
  __syncthreads();
  int r = blockIdx.x * 2 + (t >> 7);
  int c = t & 127;
  if (r >= NN) return;
  float acc = sb[c];
#pragma unroll
  for (int i = 0; i < 9; ++i) acc += in[r * 9 + i] * sW[i * 128 + c];
  out[r * 128 + c] = (_Float16)(fmaxf(acc, 0.0f) * dinv[r]);
}

// ---------- aggregation F=128 (wave/node), fp16 gather, emits interleaved split bf16 ----------
__global__ __launch_bounds__(256) void k_agg128(const half2v* __restrict__ h,
                                                unsigned short* __restrict__ Ai,
                                                const int* __restrict__ cnt,
                                                const int* __restrict__ col,
                                                const float* __restrict__ dinv) {
  int w = (blockIdx.x * 256 + threadIdx.x) >> 6;
  int lane = threadIdx.x & 63;
  if (w >= NN) return;
  half2v s = h[(size_t)w * 64 + lane];
  float ax = (float)s.x, ay = (float)s.y;
  int c = cnt[w]; if (c > CAP) c = CAP;
  const int* cl = col + w * CAP;
  int j = 0;
  for (; j + 4 <= c; j += 4) {
    int4 u = *(const int4*)(cl + j);
    half2v t0 = h[(size_t)u.x * 64 + lane];
    half2v t1 = h[(size_t)u.y * 64 + lane];
    half2v t2 = h[(size_t)u.z * 64 + lane];
    half2v t3 = h[(size_t)u.w * 64 + lane];
    ax += ((float)t0.x + (float)t1.x) + ((float)t2.x + (float)t3.x);
    ay += ((float)t0.y + (float)t1.y) + ((float)t2.y + (float)t3.y);
  }
  for (; j < c; ++j) {
    int u = cl[j];
    half2v tv = h[(size_t)u * 64 + lane];
    ax += (float)tv.x; ay += (float)tv.y;
  }
  float di = dinv[w];
  ax *= di; ay *= di;
  ushort2 hv, lv;
  split2(ax, &hv.x, &lv.x);
  split2(ay, &hv.y, &lv.y);
  size_t base = (size_t)w * 256 + (size_t)(lane >> 2) * 16 + 2 * (lane & 3);
  *(ushort2*)(Ai + base) = hv;
  *(ushort2*)(Ai + base + 8) = lv;
}

// ---------- aggregation F=256 (wave/node), fp16 gather, emits interleaved split bf16 ----------
__global__ __launch_bounds__(256) void k_agg256(const half4* __restrict__ h,
                                                unsigned short* __restrict__ Ai,
                                                const int* __restrict__ cnt,
                                                const int* __restrict__ col,
                                                const float* __restrict__ dinv) {
  int w = (blockIdx.x * 256 + threadIdx.x) >> 6;
  int lane = threadIdx.x & 63;
  if (w >= NN) return;
  half4 s = h[(size_t)w * 64 + lane];
  float ax = (float)s.x, ay = (float)s.y, az = (float)s.z, aw = (float)s.w;
  int c = cnt[w]; if (c > CAP) c = CAP;
  const int* cl = col + w * CAP;
  int j = 0;
  for (; j + 4 <= c; j += 4) {
    int4 u = *(const int4*)(cl + j);
    half4 t0 = h[(size_t)u.x * 64 + lane];
    half4 t1 = h[(size_t)u.y * 64 + lane];
    half4 t2 = h[(size_t)u.z * 64 + lane];
    half4 t3 = h[(size_t)u.w * 64 + lane];
    ax += ((float)t0.x + (float)t1.x) + ((float)t2.x + (float)t3.x);
    ay += ((float)t0.y + (float)t1.y) + ((float)t2.y + (float)t3.y);
    az += ((float)t0.z + (float)t1.z) + ((float)t2.z + (float)t3.z);
    aw += ((float)t0.w + (float)t1.w) + ((float)t2.w + (float)t3.w);
  }
  for (; j < c; ++j) {
    int u = cl[j];
    half4 tv = h[(size_t)u * 64 + lane];
    ax += (float)tv.x; ay += (float)tv.y; az += (float)tv.z; aw += (float)tv.w;
  }
  float di = dinv[w];
  ax *= di; ay *= di; az *= di; aw *= di;
  ushort4 hv, lv;
  split2(ax, &hv.x, &lv.x);
  split2(ay, &hv.y, &lv.y);
  split2(az, &hv.z, &lv.z);
  split2(aw, &hv.w, &lv.w);
  size_t base = (size_t)w * 512 + (size_t)(lane >> 1) * 16 + 4 * (lane & 1);
  *(ushort4*)(Ai + base) = hv;
  *(ushort4*)(Ai + base + 8) = lv;
}

// ---------- frag load/compute helpers for k_mm ----------
__device__ __forceinline__ void load_frags(const unsigned short* __restrict__ A,
                                           const unsigned short* __restrict__ B,
                                           const unsigned aoff[4], const unsigned boff[4],
                                           unsigned soff,
                                           bf16x8 ah[4], bf16x8 al[4],
                                           bf16x8 bh[4], bf16x8 bl[4]) {
#pragma unroll
  for (int i = 0; i < 4; ++i) {
    const unsigned short* pa = A + aoff[i] + soff;
    const unsigned short* pb = B + boff[i] + soff;
    ah[i] = *(const bf16x8*)pa;
    al[i] = *(const bf16x8*)(pa + 8);
    bh[i] = *(const bf16x8*)pb;
    bl[i] = *(const bf16x8*)(pb + 8);
  }
}
__device__ __forceinline__ void do_mfma(const bf16x8 ah[4], const bf16x8 al[4],
                                        const bf16x8 bh[4], const bf16x8 bl[4],
                                        f32x4 acc[4][4]) {
#pragma unroll
  for (int mi = 0; mi < 4; ++mi)
#pragma unroll
    for (int ni = 0; ni < 4; ++ni) {
      acc[mi][ni] = __builtin_amdgcn_mfma_f32_16x16x32_bf16(ah[mi], bh[ni], acc[mi][ni], 0, 0, 0);
      acc[mi][ni] = __builtin_amdgcn_mfma_f32_16x16x32_bf16(ah[mi], bl[ni], acc[mi][ni], 0, 0, 0);
      acc[mi][ni] = __builtin_amdgcn_mfma_f32_16x16x32_bf16(al[mi], bh[ni], acc[mi][ni], 0, 0, 0);
    }
}

// ---------- MFMA bf16x3-split GEMM, direct L2 loads + register double-buffer ----------
// A: [M][K/8][{hi8,lo8}] interleaved; B: [Nc][K/8][{hi8,lo8}] interleaved.
// block 128x128 (4 waves 2x2, 64x64/wave). K-step 32. nsteps = K/32 (4 or 8, even).
// mode 1: C(fp16) = relu(acc+bias)*dinv[row]; mode 2: fused max-pool, no C write.
__global__ __launch_bounds__(256) void k_mm(const unsigned short* __restrict__ A,
                                            const unsigned short* __restrict__ B,
                                            const float* __restrict__ bias,
                                            _Float16* __restrict__ C,
                                            const float* __restrict__ dinv,
                                            const int* __restrict__ batch,
                                            unsigned* __restrict__ gpool,
                                            int M, int K, int Nc, int mode) {
  __shared__ unsigned ldsPool[4 * 256];
  int t = threadIdx.x;
  if (mode == 2) {
    for (int i = t; i < 4 * 256; i += 256) ldsPool[i] = 0u;
    __syncthreads();
  }
  int wave = t >> 6, lane = t & 63;
  int wm = wave & 1, wn = wave >> 1;
  int rowBase = blockIdx.x * 128 + wm * 64;
  int colBase = blockIdx.y * 128 + wn * 64;
  int lm = lane & 15;
  int q  = lane >> 4;              // k8 block within 32-k step
  unsigned K2 = 2u * (unsigned)K;  // ushorts per row

  unsigned aoff[4], boff[4];
#pragma unroll
  for (int mi = 0; mi < 4; ++mi) {
    int r = rowBase + mi * 16 + lm;
    if (r > M - 1) r = M - 1;      // clamped rows never stored
    aoff[mi] = (unsigned)r * K2 + q * 16;
  }
#pragma unroll
  for (int ni = 0; ni < 4; ++ni) {
    int c = colBase + ni * 16 + lm;
    boff[ni] = (unsigned)c * K2 + q * 16;
  }

  f32x4 acc[4][4];
#pragma unroll
  for (int i = 0; i < 4; ++i)
#pragma unroll
    for (int j = 0; j < 4; ++j) acc[i][j] = (f32x4){0.f, 0.f, 0.f, 0.f};

  bf16x8 ah0[4], al0[4], bh0[4], bl0[4];
  bf16x8 ah1[4], al1[4], bh1[4], bl1[4];

  int nsteps = K >> 5;             // 4 or 8 (even)
  load_frags(A, B, aoff, boff, 0, ah0, al0, bh0, bl0);
  for (int s = 0; s < nsteps; s += 2) {
    // buffer 1 <- step s+1 (always exists: nsteps even), overlap with MFMAs on buffer 0
    load_frags(A, B, aoff, boff, (unsigned)(s + 1) * 64, ah1, al1, bh1, bl1);
    do_mfma(ah0, al0, bh0, bl0, acc);
    if (s + 2 < nsteps)
      load_frags(A, B, aoff, boff, (unsigned)(s + 2) * 64, ah0, al0, bh0, bl0);
    do_mfma(ah1, al1, bh1, bl1, acc);
  }

  // C/D layout: col = lane&15, row = (lane>>4)*4 + reg
  int rowOff = (lane >> 4) * 4;
  if (mode == 2) {
    int b0 = batch[blockIdx.x * 128];
#pragma unroll
    for (int mi = 0; mi < 4; ++mi) {
#pragma unroll
      for (int ni = 0; ni < 4; ++ni) {
        int gc = colBase + ni * 16 + lm;
        float bsv = bias[gc];
#pragma unroll
        for (int r = 0; r < 4; ++r) {
          int gr = rowBase + mi * 16 + rowOff + r;
          if (gr < M) {
            float v = acc[mi][ni][r] + bsv;
            int idx = batch[gr] - b0;
            if (idx < 0) idx = 0;
            if (idx > 3) idx = 3;
            atomicMax(&ldsPool[idx * 256 + gc], f2mono(v));
          }
        }
      }
    }
    __syncthreads();
#pragma unroll
    for (int s4 = 0; s4 < 4; ++s4) {
      unsigned mv = ldsPool[s4 * 256 + t];
      int gb = b0 + s4;
      if (mv && gb < NG) atomicMax(&gpool[gb * 256 + t], mv);
    }
  } else {
#pragma unroll
    for (int mi = 0; mi < 4; ++mi) {
#pragma unroll
      for (int ni = 0; ni < 4; ++ni) {
        int gc = colBase + ni * 16 + lm;
        float bsv = bias[gc];
#pragma unroll
        for (int r = 0; r < 4; ++r) {
          int gr = rowBase + mi * 16 + rowOff + r;
          if (gr < M) {
            float v = fmaxf(acc[mi][ni][r] + bsv, 0.0f);
            C[(size_t)gr * Nc + gc] = (_Float16)(v * dinv[gr]);
          }
        }
      }
    }
  }
}

// ---------- dense head ----------
__global__ __launch_bounds__(256) void k_head(const unsigned* __restrict__ g,
                                              const float* __restrict__ Wl2, const float* __restrict__ bl2,
                                              const float* __restrict__ Wl3, const float* __restrict__ bl3,
                                              const float* __restrict__ Wl, const float* __restrict__ bl,
                                              float* __restrict__ out) {
  __shared__ float s0[256];
  __shared__ float s1[128];
  __shared__ float s2[128];
  int b = blockIdx.x, t = threadIdx.x;
  s0[t] = mono2f(g[b * 256 + t]);
  __syncthreads();
  if (t < 128) {
    float acc = bl2[t];
    for (int k = 0; k < 256; ++k) acc += s0[k] * Wl2[k * 128 + t];
    s1[t] = fmaxf(acc, 0.0f);
  }
  __syncthreads();
  if (t < 128) {
    float acc = bl3[t];
    for (int k = 0; k < 128; ++k) acc += s1[k] * Wl3[k * 128 + t];
    s2[t] = fmaxf(acc, 0.0f);
  }
  __syncthreads();
  if (t < 10) {
    float acc = bl[t];
    for (int k = 0; k < 128; ++k) acc += s2[k] * Wl[k * 10 + t];
    out[b * 10 + t] = acc;
  }
}

extern "C" void kernel_launch(void* const* d_in, const int* in_sizes, int n_in,
                              void* d_out, int out_size, void* d_ws, size_t ws_size,
                              hipStream_t stream) {
  const float* x   = (const float*)d_in[0];
  const int* eidx  = (const int*)d_in[1];
  const int* batch = (const int*)d_in[2];
  const float* W1 = (const float*)d_in[3];   const float* b1 = (const float*)d_in[4];
  const float* W2 = (const float*)d_in[5];   const float* b2 = (const float*)d_in[6];
  const float* W3 = (const float*)d_in[7];   const float* b3 = (const float*)d_in[8];
  const float* W4 = (const float*)d_in[9];   const float* b4 = (const float*)d_in[10];
  const float* Wl2 = (const float*)d_in[11]; const float* bl2 = (const float*)d_in[12];
  const float* Wl3 = (const float*)d_in[13]; const float* bl3 = (const float*)d_in[14];
  const float* Wl  = (const float*)d_in[15]; const float* bl  = (const float*)d_in[16];
  float* out = (float*)d_out;

  // ---- workspace carve ----
  _Float16* hs = (_Float16*)d_ws;                                  // NN*256 fp16
  unsigned short* Ai = (unsigned short*)(hs + (size_t)NN * 256);   // NN*512 ushort (interleaved hi/lo)
  int* cnt  = (int*)(Ai + (size_t)NN * 512);                       // NN
  float* dinv = (float*)(cnt + NN);                                // NN
  int* col  = (int*)(dinv + NN);                                   // NN*CAP
  unsigned* g = (unsigned*)(col + (size_t)NN * CAP);               // NG*256
  unsigned short* W2i = (unsigned short*)(g + NG * 256);           // 256*256
  unsigned short* W3i = W2i + 256 * 256;                           // 256*512
  unsigned short* W4i = W3i + 256 * 512;                           // 256*512
  float* xs = (float*)hs;        // NN*9 fp32, dead before k_gemm9 writes hs
  float* agg9out = (float*)Ai;   // NN*9 fp32, dead before k_agg128 writes Ai

  const int* src = eidx;
  const int* dst = eidx + NE;

  hipMemsetAsync(cnt, 0, NN * sizeof(int), stream);
  hipMemsetAsync(g, 0, NG * 256 * sizeof(unsigned), stream);

  k_count<<<(NE + 255) / 256, 256, 0, stream>>>(src, dst, cnt, col);
  k_dinv<<<(NN + 255) / 256, 256, 0, stream>>>(cnt, dinv, x, xs);

  k_splitw<<<(128 * 256 + 255) / 256, 256, 0, stream>>>(W2, W2i, 128, 256);
  k_splitw<<<(256 * 256 + 255) / 256, 256, 0, stream>>>(W3, W3i, 256, 256);
  k_splitw<<<(256 * 256 + 255) / 256, 256, 0, stream>>>(W4, W4i, 256, 256);

  // layer 1: agg 9-dim fp32, GEMM 9->128 (+relu, *dinv, fp16 out)
  k_agg9<<<(NN + 15) / 16, 256, 0, stream>>>(xs, agg9out, cnt, col, dinv);
  k_gemm9<<<NN / 2, 256, 0, stream>>>(agg9out, W1, b1, dinv, hs);

  dim3 gmm((NN + 127) / 128, 2);

  // layer 2: fp16 gather 128-dim, MFMA GEMM 128->256
  k_agg128<<<(NN + 3) / 4, 256, 0, stream>>>((const half2v*)hs, Ai, cnt, col, dinv);
  k_mm<<<gmm, 256, 0, stream>>>(Ai, W2i, b2, hs, dinv, batch, g, NN, 128, 256, 1);

  // layer 3: fp16 gather 256-dim
  k_agg256<<<(NN + 3) / 4, 256, 0, stream>>>((const half4*)hs, Ai, cnt, col, dinv);
  k_mm<<<gmm, 256, 0, stream>>>(Ai, W3i, b3, hs, dinv, batch, g, NN, 256, 256, 1);

  // layer 4: fp16 gather 256-dim, GEMM + fused max-pool (no C write)
  k_agg256<<<(NN + 3) / 4, 256, 0, stream>>>((const half4*)hs, Ai, cnt, col, dinv);
  k_mm<<<gmm, 256, 0, stream>>>(Ai, W4i, b4, hs, dinv, batch, g, NN, 256, 256, 2);

  // head
  k_head<<<NG, 256, 0, stream>>>(g, Wl2, bl2, Wl3, bl3, Wl, bl, out);
}

// Round 7
// 483.282 us; speedup vs baseline: 1.2887x; 1.1899x over previous
//
#include <hip/hip_runtime.h>
#include <float.h>

#define NN 50000
#define NE 800000
#define NG 64
#define CAP 64

typedef __attribute__((ext_vector_type(8))) short bf16x8;
typedef __attribute__((ext_vector_type(4))) float f32x4;
typedef __attribute__((ext_vector_type(4))) _Float16 half4;
typedef __attribute__((ext_vector_type(2))) _Float16 half2v;
typedef unsigned int u32;

// ---------- helpers ----------
__device__ __forceinline__ unsigned f2mono(float f) {
  unsigned b = __float_as_uint(f);
  return (b & 0x80000000u) ? ~b : (b | 0x80000000u);
}
__device__ __forceinline__ float mono2f(unsigned u) {
  unsigned b = (u & 0x80000000u) ? (u & 0x7fffffffu) : ~u;
  return __uint_as_float(b);
}
__device__ __forceinline__ unsigned short bf16rn(float f) {
  unsigned u = __float_as_uint(f);
  unsigned r = u + 0x7FFFu + ((u >> 16) & 1u);
  return (unsigned short)(r >> 16);
}
__device__ __forceinline__ float bf2f(unsigned short h) {
  return __uint_as_float(((unsigned)h) << 16);
}
__device__ __forceinline__ void split2(float a, unsigned short* hi, unsigned short* lo) {
  unsigned short h = bf16rn(a);
  *hi = h;
  *lo = bf16rn(a - bf2f(h));
}
// async global->LDS 16B DMA (gfx950). LDS dest must be wave-uniform base + lane*16.
__device__ __forceinline__ void gl_lds16(const void* g, void* l) {
  __builtin_amdgcn_global_load_lds((const __attribute__((address_space(1))) u32*)g,
                                   (__attribute__((address_space(3))) u32*)l, 16, 0, 0);
}

// ---------- degree count + ELL adjacency fill (by dst) ----------
__global__ void k_count(const int* __restrict__ src, const int* __restrict__ dst,
                        int* __restrict__ cnt, int* __restrict__ col) {
  int e = blockIdx.x * blockDim.x + threadIdx.x;
  if (e >= NE) return;
  int d = dst[e];
  int s = src[e];
  if ((unsigned)d >= NN || (unsigned)s >= NN) return;
  int pos = atomicAdd(&cnt[d], 1);
  if (pos < CAP) col[d * CAP + pos] = s;
}

// dinv + pre-scaled input features xs = x * dinv[v]
__global__ void k_dinv(const int* __restrict__ cnt, float* __restrict__ dinv,
                       const float* __restrict__ x, float* __restrict__ xs) {
  int v = blockIdx.x * blockDim.x + threadIdx.x;
  if (v >= NN) return;
  float d = rsqrtf((float)cnt[v] + 1.0f);
  dinv[v] = d;
#pragma unroll
  for (int i = 0; i < 9; ++i) xs[v * 9 + i] = x[v * 9 + i] * d;
}

// ---------- weight split+transpose, hi/lo interleaved per-8: out[n][k8][{hi8,lo8}] ----------
__global__ void k_splitw(const float* __restrict__ W, unsigned short* __restrict__ Wi,
                         int K, int Nc) {
  int i = blockIdx.x * blockDim.x + threadIdx.x;
  if (i >= K * Nc) return;
  int k = i / Nc, n = i - k * Nc;
  float w = W[i];
  unsigned short h, l;
  split2(w, &h, &l);
  size_t base = (size_t)n * 2 * K + (size_t)(k >> 3) * 16 + (k & 7);
  Wi[base] = h;
  Wi[base + 8] = l;
}

// ---------- aggregation F=9: 16-lane group per node ----------
__global__ __launch_bounds__(256) void k_agg9(const float* __restrict__ xs,
                                              float* __restrict__ out,
                                              const int* __restrict__ cnt,
                                              const int* __restrict__ col,
                                              const float* __restrict__ dinv) {
  int v = (blockIdx.x * 256 + threadIdx.x) >> 4;
  int l = threadIdx.x & 15;
  if (v >= NN) return;
  int c = cnt[v]; if (c > CAP) c = CAP;
  const int* cl = col + v * CAP;
  float acc = (l < 9) ? xs[v * 9 + l] : 0.0f;
  int j = 0;
  for (; j + 4 <= c; j += 4) {
    int4 u = *(const int4*)(cl + j);
    float a0 = (l < 9) ? xs[u.x * 9 + l] : 0.f;
    float a1 = (l < 9) ? xs[u.y * 9 + l] : 0.f;
    float a2 = (l < 9) ? xs[u.z * 9 + l] : 0.f;
    float a3 = (l < 9) ? xs[u.w * 9 + l] : 0.f;
    acc += (a0 + a1) + (a2 + a3);
  }
  for (; j < c; ++j) {
    int u = cl[j];
    if (l < 9) acc += xs[u * 9 + l];
  }
  if (l < 9) out[v * 9 + l] = acc * dinv[v];
}

// ---------- GEMM K=9 -> 128, + bias + relu; writes fp16 (pre-scaled by dinv) ----------
__global__ __launch_bounds__(256) void k_gemm9(const float* __restrict__ in,
                                               const float* __restrict__ W,
                                               const float* __restrict__ bias,
                                               const float* __restrict__ dinv,
                                               _Float16* __restrict__ out) {
  __shared__ float sW[9 * 128];
  __shared__ float sb[128];
  int t = threadIdx.x;
  if (t < 128) sb[t] = bias[t];
  for (int i = t; i < 9 * 128; i += 256) sW[i] = W[i];
  __syncthreads();
  int r = blockIdx.x * 2 + (t >> 7);
  int c = t & 127;
  if (r >= NN) return;
  float acc = sb[c];
#pragma unroll
  for (int i = 0; i < 9; ++i) acc += in[r * 9 + i] * sW[i * 128 + c];
  out[r * 128 + c] = (_Float16)(fmaxf(acc, 0.0f) * dinv[r]);
}

// ---------- aggregation F=128 (wave/node), fp16 gather, emits interleaved split bf16 ----------
__global__ __launch_bounds__(256) void k_agg128(const half2v* __restrict__ h,
                                                unsigned short* __restrict__ Ai,
                                                const int* __restrict__ cnt,
                                                const int* __restrict__ col,
                                                const float* __restrict__ dinv) {
  int w = (blockIdx.x * 256 + threadIdx.x) >> 6;
  int lane = threadIdx.x & 63;
  if (w >= NN) return;
  half2v s = h[(size_t)w * 64 + lane];
  float ax = (float)s.x, ay = (float)s.y;
  int c = cnt[w]; if (c > CAP) c = CAP;
  const int* cl = col + w * CAP;
  int j = 0;
  for (; j + 4 <= c; j += 4) {
    int4 u = *(const int4*)(cl + j);
    half2v t0 = h[(size_t)u.x * 64 + lane];
    half2v t1 = h[(size_t)u.y * 64 + lane];
    half2v t2 = h[(size_t)u.z * 64 + lane];
    half2v t3 = h[(size_t)u.w * 64 + lane];
    ax += ((float)t0.x + (float)t1.x) + ((float)t2.x + (float)t3.x);
    ay += ((float)t0.y + (float)t1.y) + ((float)t2.y + (float)t3.y);
  }
  for (; j < c; ++j) {
    int u = cl[j];
    half2v tv = h[(size_t)u * 64 + lane];
    ax += (float)tv.x; ay += (float)tv.y;
  }
  float di = dinv[w];
  ax *= di; ay *= di;
  ushort2 hv, lv;
  split2(ax, &hv.x, &lv.x);
  split2(ay, &hv.y, &lv.y);
  size_t base = (size_t)w * 256 + (size_t)(lane >> 2) * 16 + 2 * (lane & 3);
  *(ushort2*)(Ai + base) = hv;
  *(ushort2*)(Ai + base + 8) = lv;
}

// ---------- aggregation F=256 (wave/node), fp16 gather, emits interleaved split bf16 ----------
__global__ __launch_bounds__(256) void k_agg256(const half4* __restrict__ h,
                                                unsigned short* __restrict__ Ai,
                                                const int* __restrict__ cnt,
                                                const int* __restrict__ col,
                                                const float* __restrict__ dinv) {
  int w = (blockIdx.x * 256 + threadIdx.x) >> 6;
  int lane = threadIdx.x & 63;
  if (w >= NN) return;
  half4 s = h[(size_t)w * 64 + lane];
  float ax = (float)s.x, ay = (float)s.y, az = (float)s.z, aw = (float)s.w;
  int c = cnt[w]; if (c > CAP) c = CAP;
  const int* cl = col + w * CAP;
  int j = 0;
  for (; j + 4 <= c; j += 4) {
    int4 u = *(const int4*)(cl + j);
    half4 t0 = h[(size_t)u.x * 64 + lane];
    half4 t1 = h[(size_t)u.y * 64 + lane];
    half4 t2 = h[(size_t)u.z * 64 + lane];
    half4 t3 = h[(size_t)u.w * 64 + lane];
    ax += ((float)t0.x + (float)t1.x) + ((float)t2.x + (float)t3.x);
    ay += ((float)t0.y + (float)t1.y) + ((float)t2.y + (float)t3.y);
    az += ((float)t0.z + (float)t1.z) + ((float)t2.z + (float)t3.z);
    aw += ((float)t0.w + (float)t1.w) + ((float)t2.w + (float)t3.w);
  }
  for (; j < c; ++j) {
    int u = cl[j];
    half4 tv = h[(size_t)u * 64 + lane];
    ax += (float)tv.x; ay += (float)tv.y; az += (float)tv.z; aw += (float)tv.w;
  }
  float di = dinv[w];
  ax *= di; ay *= di; az *= di; aw *= di;
  ushort4 hv, lv;
  split2(ax, &hv.x, &lv.x);
  split2(ay, &hv.y, &lv.y);
  split2(az, &hv.z, &lv.z);
  split2(aw, &hv.w, &lv.w);
  size_t base = (size_t)w * 512 + (size_t)(lane >> 1) * 16 + 4 * (lane & 1);
  *(ushort4*)(Ai + base) = hv;
  *(ushort4*)(Ai + base + 8) = lv;
}

// ---------- MFMA bf16x3-split GEMM, m97-style LDS staging via global_load_lds ----------
// A: [M][K/8][{hi8,lo8}] interleaved; B: [Nc][K/8][{hi8,lo8}] interleaved.
// block 128x128 (4 waves 2x2, 64x64/wave). K-step 32 = 8 segs of 16B per row.
// LDS tile: [128 rows][8 segs], seg j of row r holds global seg (j ^ (r&7))  -- XOR
// swizzle realized via per-lane DMA source addresses (LDS side must stay dense).
// mode 1: C(fp16) = relu(acc+bias)*dinv[row]; mode 2: fused max-pool, no C write.
__global__ __launch_bounds__(256) void k_mm(const unsigned short* __restrict__ A,
                                            const unsigned short* __restrict__ B,
                                            const float* __restrict__ bias,
                                            _Float16* __restrict__ C,
                                            const float* __restrict__ dinv,
                                            const int* __restrict__ batch,
                                            unsigned* __restrict__ gpool,
                                            int M, int K, int Nc, int mode) {
  __shared__ __align__(16) unsigned short Al[128 * 64];   // 16 KB
  __shared__ __align__(16) unsigned short Bl[128 * 64];   // 16 KB
  int t = threadIdx.x;
  int wave = t >> 6, lane = t & 63;
  int wm = wave & 1, wn = wave >> 1;
  int rowBase = blockIdx.x * 128;
  int colBase = blockIdx.y * 128;
  int lm = lane & 15;
  int q  = lane >> 4;                  // k-octet within 32-k step
  unsigned K2 = 2u * (unsigned)K;      // ushorts per row

  // staging geometry: wave stages rows [wave*32 + c*8, +8), lane -> (row lane>>3, seg lane&7)
  int srl  = wave * 32 + (lane >> 3);  // c adds 8
  int sj   = lane & 7;
  int ssw  = srl & 7;                  // note: (srl + 8c) & 7 == srl & 7

  f32x4 acc[4][4];
#pragma unroll
  for (int i = 0; i < 4; ++i)
#pragma unroll
    for (int j = 0; j < 4; ++j) acc[i][j] = (f32x4){0.f, 0.f, 0.f, 0.f};

  int nsteps = K >> 5;
  for (int s = 0; s < nsteps; ++s) {
    __syncthreads();                   // previous step's ds_reads complete
#pragma unroll
    for (int c = 0; c < 4; ++c) {
      int rl = srl + c * 8;
      int gseg = s * 8 + (sj ^ ssw);
      int ga = rowBase + rl; if (ga > M - 1) ga = M - 1;
      gl_lds16(A + (size_t)ga * K2 + gseg * 8, Al + (wave * 32 + c * 8) * 64 + lane * 8);
      int gb = colBase + rl;
      gl_lds16(B + (size_t)gb * K2 + gseg * 8, Bl + (wave * 32 + c * 8) * 64 + lane * 8);
    }
    __syncthreads();                   // drains DMA (vmcnt) + orders LDS

    bf16x8 bh[4], blv[4];
#pragma unroll
    for (int ni = 0; ni < 4; ++ni) {
      int r = wn * 64 + ni * 16 + lm;
      const unsigned short* p = Bl + r * 64;
      int sw = r & 7;
      bh[ni]  = *(const bf16x8*)(p + ((2 * q) ^ sw) * 8);
      blv[ni] = *(const bf16x8*)(p + ((2 * q + 1) ^ sw) * 8);
    }
#pragma unroll
    for (int mi = 0; mi < 4; ++mi) {
      int r = wm * 64 + mi * 16 + lm;
      const unsigned short* p = Al + r * 64;
      int sw = r & 7;
      bf16x8 ah = *(const bf16x8*)(p + ((2 * q) ^ sw) * 8);
      bf16x8 al = *(const bf16x8*)(p + ((2 * q + 1) ^ sw) * 8);
#pragma unroll
      for (int ni = 0; ni < 4; ++ni) {
        acc[mi][ni] = __builtin_amdgcn_mfma_f32_16x16x32_bf16(ah, bh[ni],  acc[mi][ni], 0, 0, 0);
        acc[mi][ni] = __builtin_amdgcn_mfma_f32_16x16x32_bf16(ah, blv[ni], acc[mi][ni], 0, 0, 0);
        acc[mi][ni] = __builtin_amdgcn_mfma_f32_16x16x32_bf16(al, bh[ni],  acc[mi][ni], 0, 0, 0);
      }
    }
  }

  // C/D layout: col = lane&15, row = (lane>>4)*4 + reg
  int rowOff = (lane >> 4) * 4;
  if (mode == 2) {
    __syncthreads();                   // staging LDS dead -> reuse as pool
    unsigned* ldsPool = (unsigned*)Al;
    for (int i = t; i < 4 * 256; i += 256) ldsPool[i] = 0u;
    __syncthreads();
    int b0 = batch[rowBase];
#pragma unroll
    for (int mi = 0; mi < 4; ++mi) {
#pragma unroll
      for (int ni = 0; ni < 4; ++ni) {
        int gc = colBase + wn * 64 + ni * 16 + lm;
        float bsv = bias[gc];
#pragma unroll
        for (int r = 0; r < 4; ++r) {
          int gr = rowBase + wm * 64 + mi * 16 + rowOff + r;
          if (gr < M) {
            float v = acc[mi][ni][r] + bsv;
            int idx = batch[gr] - b0;
            if (idx < 0) idx = 0;
            if (idx > 3) idx = 3;
            atomicMax(&ldsPool[idx * 256 + gc], f2mono(v));
          }
        }
      }
    }
    __syncthreads();
#pragma unroll
    for (int s4 = 0; s4 < 4; ++s4) {
      unsigned mv = ldsPool[s4 * 256 + t];
      int gb = b0 + s4;
      if (mv && gb < NG) atomicMax(&gpool[gb * 256 + t], mv);
    }
  } else {
#pragma unroll
    for (int mi = 0; mi < 4; ++mi) {
#pragma unroll
      for (int ni = 0; ni < 4; ++ni) {
        int gc = colBase + wn * 64 + ni * 16 + lm;
        float bsv = bias[gc];
#pragma unroll
        for (int r = 0; r < 4; ++r) {
          int gr = rowBase + wm * 64 + mi * 16 + rowOff + r;
          if (gr < M) {
            float v = fmaxf(acc[mi][ni][r] + bsv, 0.0f);
            C[(size_t)gr * Nc + gc] = (_Float16)(v * dinv[gr]);
          }
        }
      }
    }
  }
}

// ---------- dense head ----------
__global__ __launch_bounds__(256) void k_head(const unsigned* __restrict__ g,
                                              const float* __restrict__ Wl2, const float* __restrict__ bl2,
                                              const float* __restrict__ Wl3, const float* __restrict__ bl3,
                                              const float* __restrict__ Wl, const float* __restrict__ bl,
                                              float* __restrict__ out) {
  __shared__ float s0[256];
  __shared__ float s1[128];
  __shared__ float s2[128];
  int b = blockIdx.x, t = threadIdx.x;
  s0[t] = mono2f(g[b * 256 + t]);
  __syncthreads();
  if (t < 128) {
    float acc = bl2[t];
    for (int k = 0; k < 256; ++k) acc += s0[k] * Wl2[k * 128 + t];
    s1[t] = fmaxf(acc, 0.0f);
  }
  __syncthreads();
  if (t < 128) {
    float acc = bl3[t];
    for (int k = 0; k < 128; ++k) acc += s1[k] * Wl3[k * 128 + t];
    s2[t] = fmaxf(acc, 0.0f);
  }
  __syncthreads();
  if (t < 10) {
    float acc = bl[t];
    for (int k = 0; k < 128; ++k) acc += s2[k] * Wl[k * 10 + t];
    out[b * 10 + t] = acc;
  }
}

extern "C" void kernel_launch(void* const* d_in, const int* in_sizes, int n_in,
                              void* d_out, int out_size, void* d_ws, size_t ws_size,
                              hipStream_t stream) {
  const float* x   = (const float*)d_in[0];
  const int* eidx  = (const int*)d_in[1];
  const int* batch = (const int*)d_in[2];
  const float* W1 = (const float*)d_in[3];   const float* b1 = (const float*)d_in[4];
  const float* W2 = (const float*)d_in[5];   const float* b2 = (const float*)d_in[6];
  const float* W3 = (const float*)d_in[7];   const float* b3 = (const float*)d_in[8];
  const float* W4 = (const float*)d_in[9];   const float* b4 = (const float*)d_in[10];
  const float* Wl2 = (const float*)d_in[11]; const float* bl2 = (const float*)d_in[12];
  const float* Wl3 = (const float*)d_in[13]; const float* bl3 = (const float*)d_in[14];
  const float* Wl  = (const float*)d_in[15]; const float* bl  = (const float*)d_in[16];
  float* out = (float*)d_out;

  // ---- workspace carve ----
  _Float16* hs = (_Float16*)d_ws;                                  // NN*256 fp16
  unsigned short* Ai = (unsigned short*)(hs + (size_t)NN * 256);   // NN*512 ushort (interleaved hi/lo)
  int* cnt  = (int*)(Ai + (size_t)NN * 512);                       // NN
  float* dinv = (float*)(cnt + NN);                                // NN
  int* col  = (int*)(dinv + NN);                                   // NN*CAP
  unsigned* g = (unsigned*)(col + (size_t)NN * CAP);               // NG*256
  unsigned short* W2i = (unsigned short*)(g + NG * 256);           // 256*256
  unsigned short* W3i = W2i + 256 * 256;                           // 256*512
  unsigned short* W4i = W3i + 256 * 512;                           // 256*512
  float* xs = (float*)hs;        // NN*9 fp32, dead before k_gemm9 writes hs
  float* agg9out = (float*)Ai;   // NN*9 fp32, dead before k_agg128 writes Ai

  const int* src = eidx;
  const int* dst = eidx + NE;

  hipMemsetAsync(cnt, 0, NN * sizeof(int), stream);
  hipMemsetAsync(g, 0, NG * 256 * sizeof(unsigned), stream);

  k_count<<<(NE + 255) / 256, 256, 0, stream>>>(src, dst, cnt, col);
  k_dinv<<<(NN + 255) / 256, 256, 0, stream>>>(cnt, dinv, x, xs);

  k_splitw<<<(128 * 256 + 255) / 256, 256, 0, stream>>>(W2, W2i, 128, 256);
  k_splitw<<<(256 * 256 + 255) / 256, 256, 0, stream>>>(W3, W3i, 256, 256);
  k_splitw<<<(256 * 256 + 255) / 256, 256, 0, stream>>>(W4, W4i, 256, 256);

  // layer 1: agg 9-dim fp32, GEMM 9->128 (+relu, *dinv, fp16 out)
  k_agg9<<<(NN + 15) / 16, 256, 0, stream>>>(xs, agg9out, cnt, col, dinv);
  k_gemm9<<<NN / 2, 256, 0, stream>>>(agg9out, W1, b1, dinv, hs);

  dim3 gmm((NN + 127) / 128, 2);

  // layer 2: fp16 gather 128-dim, MFMA GEMM 128->256
  k_agg128<<<(NN + 3) / 4, 256, 0, stream>>>((const half2v*)hs, Ai, cnt, col, dinv);
  k_mm<<<gmm, 256, 0, stream>>>(Ai, W2i, b2, hs, dinv, batch, g, NN, 128, 256, 1);

  // layer 3: fp16 gather 256-dim
  k_agg256<<<(NN + 3) / 4, 256, 0, stream>>>((const half4*)hs, Ai, cnt, col, dinv);
  k_mm<<<gmm, 256, 0, stream>>>(Ai, W3i, b3, hs, dinv, batch, g, NN, 256, 256, 1);

  // layer 4: fp16 gather 256-dim, GEMM + fused max-pool (no C write)
  k_agg256<<<(NN + 3) / 4, 256, 0, stream>>>((const half4*)hs, Ai, cnt, col, dinv);
  k_mm<<<gmm, 256, 0, stream>>>(Ai, W4i, b4, hs, dinv, batch, g, NN, 256, 256, 2);

  // head
  k_head<<<NG, 256, 0, stream>>>(g, Wl2, bl2, Wl3, bl3, Wl, bl, out);
}

// Round 8
// 455.020 us; speedup vs baseline: 1.3688x; 1.0621x over previous
//
#include <hip/hip_runtime.h>
#include <float.h>

#define NN 50000
#define NE 800000
#define NG 64
#define CAP 64

typedef __attribute__((ext_vector_type(8))) _Float16 f16x8;
typedef __attribute__((ext_vector_type(4))) float f32x4;
typedef __attribute__((ext_vector_type(4))) _Float16 half4;
typedef __attribute__((ext_vector_type(2))) _Float16 half2v;
typedef unsigned int u32;

// ---------- helpers ----------
__device__ __forceinline__ unsigned f2mono(float f) {
  unsigned b = __float_as_uint(f);
  return (b & 0x80000000u) ? ~b : (b | 0x80000000u);
}
__device__ __forceinline__ float mono2f(unsigned u) {
  unsigned b = (u & 0x80000000u) ? (u & 0x7fffffffu) : ~u;
  return __uint_as_float(b);
}
// async global->LDS 16B DMA (gfx950). LDS dest must be wave-uniform base + lane*16.
__device__ __forceinline__ void gl_lds16(const void* g, void* l) {
  __builtin_amdgcn_global_load_lds((const __attribute__((address_space(1))) u32*)g,
                                   (__attribute__((address_space(3))) u32*)l, 16, 0, 0);
}

// ---------- degree count + ELL adjacency fill (by dst) ----------
__global__ void k_count(const int* __restrict__ src, const int* __restrict__ dst,
                        int* __restrict__ cnt, int* __restrict__ col) {
  int e = blockIdx.x * blockDim.x + threadIdx.x;
  if (e >= NE) return;
  int d = dst[e];
  int s = src[e];
  if ((unsigned)d >= NN || (unsigned)s >= NN) return;
  int pos = atomicAdd(&cnt[d], 1);
  if (pos < CAP) col[d * CAP + pos] = s;
}

// dinv + pre-scaled input features xs = x * dinv[v]
__global__ void k_dinv(const int* __restrict__ cnt, float* __restrict__ dinv,
                       const float* __restrict__ x, float* __restrict__ xs) {
  int v = blockIdx.x * blockDim.x + threadIdx.x;
  if (v >= NN) return;
  float d = rsqrtf((float)cnt[v] + 1.0f);
  dinv[v] = d;
#pragma unroll
  for (int i = 0; i < 9; ++i) xs[v * 9 + i] = x[v * 9 + i] * d;
}

// ---------- weight split+transpose: W[K][Nc] fp32 -> Wh/Wl[Nc][K] fp16 (w = wh + wl) ----------
__global__ void k_splitw(const float* __restrict__ W, _Float16* __restrict__ Wh,
                         _Float16* __restrict__ Wl, int K, int Nc) {
  int i = blockIdx.x * blockDim.x + threadIdx.x;
  if (i >= K * Nc) return;
  int k = i / Nc, n = i - k * Nc;
  float w = W[i];
  _Float16 h = (_Float16)w;
  _Float16 l = (_Float16)(w - (float)h);
  Wh[(size_t)n * K + k] = h;
  Wl[(size_t)n * K + k] = l;
}

// ---------- aggregation F=9: 16-lane group per node ----------
__global__ __launch_bounds__(256) void k_agg9(const float* __restrict__ xs,
                                              float* __restrict__ out,
                                              const int* __restrict__ cnt,
                                              const int* __restrict__ col,
                                              const float* __restrict__ dinv) {
  int v = (blockIdx.x * 256 + threadIdx.x) >> 4;
  int l = threadIdx.x & 15;
  if (v >= NN) return;
  int c = cnt[v]; if (c > CAP) c = CAP;
  const int* cl = col + v * CAP;
  float acc = (l < 9) ? xs[v * 9 + l] : 0.0f;
  int j = 0;
  for (; j + 4 <= c; j += 4) {
    int4 u = *(const int4*)(cl + j);
    float a0 = (l < 9) ? xs[u.x * 9 + l] : 0.f;
    float a1 = (l < 9) ? xs[u.y * 9 + l] : 0.f;
    float a2 = (l < 9) ? xs[u.z * 9 + l] : 0.f;
    float a3 = (l < 9) ? xs[u.w * 9 + l] : 0.f;
    acc += (a0 + a1) + (a2 + a3);
  }
  for (; j < c; ++j) {
    int u = cl[j];
    if (l < 9) acc += xs[u * 9 + l];
  }
  if (l < 9) out[v * 9 + l] = acc * dinv[v];
}

// ---------- GEMM K=9 -> 128, + bias + relu; writes fp16 (pre-scaled by dinv) ----------
__global__ __launch_bounds__(256) void k_gemm9(const float* __restrict__ in,
                                               const float* __restrict__ W,
                                               const float* __restrict__ bias,
                                               const float* __restrict__ dinv,
                                               _Float16* __restrict__ out) {
  __shared__ float sW[9 * 128];
  __shared__ float sb[128];
  int t = threadIdx.x;
  if (t < 128) sb[t] = bias[t];
  for (int i = t; i < 9 * 128; i += 256) sW[i] = W[i];
  __syncthreads();
  int r = blockIdx.x * 2 + (t >> 7);
  int c = t & 127;
  if (r >= NN) return;
  float acc = sb[c];
#pragma unroll
  for (int i = 0; i < 9; ++i) acc += in[r * 9 + i] * sW[i * 128 + c];
  out[r * 128 + c] = (_Float16)(fmaxf(acc, 0.0f) * dinv[r]);
}

// ---------- aggregation F=128 (wave/node), fp16 gather, fp16 out (natural layout) ----------
__global__ __launch_bounds__(256) void k_agg128(const half2v* __restrict__ h,
                                                half2v* __restrict__ out,
                                                const int* __restrict__ cnt,
                                                const int* __restrict__ col,
                                                const float* __restrict__ dinv) {
  int w = (blockIdx.x * 256 + threadIdx.x) >> 6;
  int lane = threadIdx.x & 63;
  if (w >= NN) return;
  half2v s = h[(size_t)w * 64 + lane];
  float ax = (float)s.x, ay = (float)s.y;
  int c = cnt[w]; if (c > CAP) c = CAP;
  const int* cl = col + w * CAP;
  int j = 0;
  for (; j + 4 <= c; j += 4) {
    int4 u = *(const int4*)(cl + j);
    half2v t0 = h[(size_t)u.x * 64 + lane];
    half2v t1 = h[(size_t)u.y * 64 + lane];
    half2v t2 = h[(size_t)u.z * 64 + lane];
    half2v t3 = h[(size_t)u.w * 64 + lane];
    ax += ((float)t0.x + (float)t1.x) + ((float)t2.x + (float)t3.x);
    ay += ((float)t0.y + (float)t1.y) + ((float)t2.y + (float)t3.y);
  }
  for (; j < c; ++j) {
    int u = cl[j];
    half2v tv = h[(size_t)u * 64 + lane];
    ax += (float)tv.x; ay += (float)tv.y;
  }
  float di = dinv[w];
  half2v o;
  o.x = (_Float16)(ax * di);
  o.y = (_Float16)(ay * di);
  out[(size_t)w * 64 + lane] = o;
}

// ---------- aggregation F=256 (wave/node), fp16 gather, fp16 out (natural layout) ----------
__global__ __launch_bounds__(256) void k_agg256(const half4* __restrict__ h,
                                                half4* __restrict__ out,
                                                const int* __restrict__ cnt,
                                                const int* __restrict__ col,
                                                const float* __restrict__ dinv) {
  int w = (blockIdx.x * 256 + threadIdx.x) >> 6;
  int lane = threadIdx.x & 63;
  if (w >= NN) return;
  half4 s = h[(size_t)w * 64 + lane];
  float ax = (float)s.x, ay = (float)s.y, az = (float)s.z, aw = (float)s.w;
  int c = cnt[w]; if (c > CAP) c = CAP;
  const int* cl = col + w * CAP;
  int j = 0;
  for (; j + 4 <= c; j += 4) {
    int4 u = *(const int4*)(cl + j);
    half4 t0 = h[(size_t)u.x * 64 + lane];
    half4 t1 = h[(size_t)u.y * 64 + lane];
    half4 t2 = h[(size_t)u.z * 64 + lane];
    half4 t3 = h[(size_t)u.w * 64 + lane];
    ax += ((float)t0.x + (float)t1.x) + ((float)t2.x + (float)t3.x);
    ay += ((float)t0.y + (float)t1.y) + ((float)t2.y + (float)t3.y);
    az += ((float)t0.z + (float)t1.z) + ((float)t2.z + (float)t3.z);
    aw += ((float)t0.w + (float)t1.w) + ((float)t2.w + (float)t3.w);
  }
  for (; j < c; ++j) {
    int u = cl[j];
    half4 tv = h[(size_t)u * 64 + lane];
    ax += (float)tv.x; ay += (float)tv.y; az += (float)tv.z; aw += (float)tv.w;
  }
  float di = dinv[w];
  half4 o;
  o.x = (_Float16)(ax * di);
  o.y = (_Float16)(ay * di);
  o.z = (_Float16)(az * di);
  o.w = (_Float16)(aw * di);
  out[(size_t)w * 64 + lane] = o;
}

// ---------- MFMA fp16 hi/lo-weight GEMM, DMA LDS staging (m97 structure) ----------
// A: [M][K] fp16 (natural layout = agg output). Wh/Wl: [Nc][K] fp16.
// block 128x128 (4 waves 2x2, 64x64/wave). Iteration = 64 k = 8 segs of 16B/row.
// Three 16KB LDS tiles (A, Bh, Bl), identical XOR-8 swizzle: LDS[r][j] = G[r][j^(r&7)].
// mode 1: C(fp16) = relu(acc+bias)*dinv[row]; mode 2: fused max-pool, no C write.
__global__ __launch_bounds__(256) void k_mm(const _Float16* __restrict__ A,
                                            const _Float16* __restrict__ Bh,
                                            const _Float16* __restrict__ Bl,
                                            const float* __restrict__ bias,
                                            _Float16* __restrict__ C,
                                            const float* __restrict__ dinv,
                                            const int* __restrict__ batch,
                                            unsigned* __restrict__ gpool,
                                            int M, int K, int Nc, int mode) {
  __shared__ __align__(16) _Float16 Alds[128 * 64];   // 16 KB
  __shared__ __align__(16) _Float16 Bhl[128 * 64];    // 16 KB
  __shared__ __align__(16) _Float16 Bll[128 * 64];    // 16 KB
  int t = threadIdx.x;
  int wave = t >> 6, lane = t & 63;
  int wm = wave & 1, wn = wave >> 1;
  int rowBase = blockIdx.x * 128;
  int colBase = blockIdx.y * 128;
  int lm = lane & 15;
  int q  = lane >> 4;                  // k-octet within a 32-k sub-step

  // staging geometry: lane -> (local row lane>>3 within 8-row group, seg lane&7)
  int srl = wave * 32 + (lane >> 3);   // c adds 8
  int sj  = lane & 7;
  int ssw = lane >> 3;                 // (srl + 8c) & 7 == lane>>3
  int gseg = sj ^ ssw;

  f32x4 acc[4][4];
#pragma unroll
  for (int i = 0; i < 4; ++i)
#pragma unroll
    for (int j = 0; j < 4; ++j) acc[i][j] = (f32x4){0.f, 0.f, 0.f, 0.f};

  int nit = K >> 6;                    // 2 (K=128) or 4 (K=256)
  for (int it = 0; it < nit; ++it) {
    __syncthreads();                   // previous iteration's ds_reads complete
#pragma unroll
    for (int c = 0; c < 4; ++c) {
      int rl = srl + c * 8;
      int ga = rowBase + rl; if (ga > M - 1) ga = M - 1;
      int gb = colBase + rl;
      unsigned off = (unsigned)it * 64 + gseg * 8;
      int ldst = (wave * 32 + c * 8) * 64 + lane * 8;
      gl_lds16(A  + (size_t)ga * K + off, Alds + ldst);
      gl_lds16(Bh + (size_t)gb * K + off, Bhl + ldst);
      gl_lds16(Bl + (size_t)gb * K + off, Bll + ldst);
    }
    __syncthreads();                   // drains DMA + orders LDS

#pragma unroll
    for (int s2 = 0; s2 < 2; ++s2) {
      int slotq = ((s2 << 2) | q);
      f16x8 vbh[4], vbl[4];
#pragma unroll
      for (int ni = 0; ni < 4; ++ni) {
        int rB = wn * 64 + ni * 16 + lm;
        int slot = slotq ^ (lm & 7);
        vbh[ni] = *(const f16x8*)(Bhl + rB * 64 + slot * 8);
        vbl[ni] = *(const f16x8*)(Bll + rB * 64 + slot * 8);
      }
#pragma unroll
      for (int mi = 0; mi < 4; ++mi) {
        int rA = wm * 64 + mi * 16 + lm;
        int slot = slotq ^ (lm & 7);
        f16x8 va = *(const f16x8*)(Alds + rA * 64 + slot * 8);
#pragma unroll
        for (int ni = 0; ni < 4; ++ni) {
          acc[mi][ni] = __builtin_amdgcn_mfma_f32_16x16x32_f16(va, vbh[ni], acc[mi][ni], 0, 0, 0);
          acc[mi][ni] = __builtin_amdgcn_mfma_f32_16x16x32_f16(va, vbl[ni], acc[mi][ni], 0, 0, 0);
        }
      }
    }
  }

  // C/D layout: col = lane&15, row = (lane>>4)*4 + reg
  int rowOff = (lane >> 4) * 4;
  if (mode == 2) {
    __syncthreads();                   // staging LDS dead -> reuse as pool
    unsigned* ldsPool = (unsigned*)Alds;
    for (int i = t; i < 4 * 256; i += 256) ldsPool[i] = 0u;
    __syncthreads();
    int b0 = batch[rowBase];
#pragma unroll
    for (int mi = 0; mi < 4; ++mi) {
#pragma unroll
      for (int ni = 0; ni < 4; ++ni) {
        int gc = colBase + wn * 64 + ni * 16 + lm;
        float bsv = bias[gc];
#pragma unroll
        for (int r = 0; r < 4; ++r) {
          int gr = rowBase + wm * 64 + mi * 16 + rowOff + r;
          if (gr < M) {
            float v = acc[mi][ni][r] + bsv;
            int idx = batch[gr] - b0;
            if (idx < 0) idx = 0;
            if (idx > 3) idx = 3;
            atomicMax(&ldsPool[idx * 256 + gc], f2mono(v));
          }
        }
      }
    }
    __syncthreads();
#pragma unroll
    for (int s4 = 0; s4 < 4; ++s4) {
      unsigned mv = ldsPool[s4 * 256 + t];
      int gb = b0 + s4;
      if (mv && gb < NG) atomicMax(&gpool[gb * 256 + t], mv);
    }
  } else {
#pragma unroll
    for (int mi = 0; mi < 4; ++mi) {
#pragma unroll
      for (int ni = 0; ni < 4; ++ni) {
        int gc = colBase + wn * 64 + ni * 16 + lm;
        float bsv = bias[gc];
#pragma unroll
        for (int r = 0; r < 4; ++r) {
          int gr = rowBase + wm * 64 + mi * 16 + rowOff + r;
          if (gr < M) {
            float v = fmaxf(acc[mi][ni][r] + bsv, 0.0f);
            C[(size_t)gr * Nc + gc] = (_Float16)(v * dinv[gr]);
          }
        }
      }
    }
  }
}

// ---------- dense head ----------
__global__ __launch_bounds__(256) void k_head(const unsigned* __restrict__ g,
                                              const float* __restrict__ Wl2, const float* __restrict__ bl2,
                                              const float* __restrict__ Wl3, const float* __restrict__ bl3,
                                              const float* __restrict__ Wl, const float* __restrict__ bl,
                                              float* __restrict__ out) {
  __shared__ float s0[256];
  __shared__ float s1[128];
  __shared__ float s2[128];
  int b = blockIdx.x, t = threadIdx.x;
  s0[t] = mono2f(g[b * 256 + t]);
  __syncthreads();
  if (t < 128) {
    float acc = bl2[t];
    for (int k = 0; k < 256; ++k) acc += s0[k] * Wl2[k * 128 + t];
    s1[t] = fmaxf(acc, 0.0f);
  }
  __syncthreads();
  if (t < 128) {
    float acc = bl3[t];
    for (int k = 0; k < 128; ++k) acc += s1[k] * Wl3[k * 128 + t];
    s2[t] = fmaxf(acc, 0.0f);
  }
  __syncthreads();
  if (t < 10) {
    float acc = bl[t];
    for (int k = 0; k < 128; ++k) acc += s2[k] * Wl[k * 10 + t];
    out[b * 10 + t] = acc;
  }
}

extern "C" void kernel_launch(void* const* d_in, const int* in_sizes, int n_in,
                              void* d_out, int out_size, void* d_ws, size_t ws_size,
                              hipStream_t stream) {
  const float* x   = (const float*)d_in[0];
  const int* eidx  = (const int*)d_in[1];
  const int* batch = (const int*)d_in[2];
  const float* W1 = (const float*)d_in[3];   const float* b1 = (const float*)d_in[4];
  const float* W2 = (const float*)d_in[5];   const float* b2 = (const float*)d_in[6];
  const float* W3 = (const float*)d_in[7];   const float* b3 = (const float*)d_in[8];
  const float* W4 = (const float*)d_in[9];   const float* b4 = (const float*)d_in[10];
  const float* Wl2 = (const float*)d_in[11]; const float* bl2 = (const float*)d_in[12];
  const float* Wl3 = (const float*)d_in[13]; const float* bl3 = (const float*)d_in[14];
  const float* Wl  = (const float*)d_in[15]; const float* bl  = (const float*)d_in[16];
  float* out = (float*)d_out;

  // ---- workspace carve ----
  _Float16* bufA = (_Float16*)d_ws;                                // NN*256 fp16
  _Float16* bufB = bufA + (size_t)NN * 256;                        // NN*256 fp16
  int* cnt  = (int*)(bufB + (size_t)NN * 256);                     // NN
  float* dinv = (float*)(cnt + NN);                                // NN
  int* col  = (int*)(dinv + NN);                                   // NN*CAP
  unsigned* g = (unsigned*)(col + (size_t)NN * CAP);               // NG*256
  _Float16* W2h = (_Float16*)(g + NG * 256);                       // 256*128
  _Float16* W2l = W2h + 256 * 128;
  _Float16* W3h = W2l + 256 * 128;                                 // 256*256
  _Float16* W3l = W3h + 256 * 256;
  _Float16* W4h = W3l + 256 * 256;
  _Float16* W4l = W4h + 256 * 256;
  float* xs = (float*)bufA;        // NN*9 fp32, dead before k_gemm9 writes bufA
  float* agg9out = (float*)bufB;   // NN*9 fp32, dead before k_agg128 writes bufB

  const int* src = eidx;
  const int* dst = eidx + NE;

  hipMemsetAsync(cnt, 0, NN * sizeof(int), stream);
  hipMemsetAsync(g, 0, NG * 256 * sizeof(unsigned), stream);

  k_count<<<(NE + 255) / 256, 256, 0, stream>>>(src, dst, cnt, col);
  k_dinv<<<(NN + 255) / 256, 256, 0, stream>>>(cnt, dinv, x, xs);

  k_splitw<<<(128 * 256 + 255) / 256, 256, 0, stream>>>(W2, W2h, W2l, 128, 256);
  k_splitw<<<(256 * 256 + 255) / 256, 256, 0, stream>>>(W3, W3h, W3l, 256, 256);
  k_splitw<<<(256 * 256 + 255) / 256, 256, 0, stream>>>(W4, W4h, W4l, 256, 256);

  // layer 1: agg 9-dim fp32, GEMM 9->128 (+relu, *dinv, fp16 out to bufA)
  k_agg9<<<(NN + 15) / 16, 256, 0, stream>>>(xs, agg9out, cnt, col, dinv);
  k_gemm9<<<NN / 2, 256, 0, stream>>>(agg9out, W1, b1, dinv, bufA);

  dim3 gmm((NN + 127) / 128, 2);

  // layer 2: gather 128-dim bufA->bufB, MFMA GEMM 128->256 bufB->bufA
  k_agg128<<<(NN + 3) / 4, 256, 0, stream>>>((const half2v*)bufA, (half2v*)bufB, cnt, col, dinv);
  k_mm<<<gmm, 256, 0, stream>>>(bufB, W2h, W2l, b2, bufA, dinv, batch, g, NN, 128, 256, 1);

  // layer 3: gather 256-dim bufA->bufB, GEMM bufB->bufA
  k_agg256<<<(NN + 3) / 4, 256, 0, stream>>>((const half4*)bufA, (half4*)bufB, cnt, col, dinv);
  k_mm<<<gmm, 256, 0, stream>>>(bufB, W3h, W3l, b3, bufA, dinv, batch, g, NN, 256, 256, 1);

  // layer 4: gather 256-dim bufA->bufB, GEMM + fused max-pool (no C write)
  k_agg256<<<(NN + 3) / 4, 256, 0, stream>>>((const half4*)bufA, (half4*)bufB, cnt, col, dinv);
  k_mm<<<gmm, 256, 0, stream>>>(bufB, W4h, W4l, b4, bufA, dinv, batch, g, NN, 256, 256, 2);

  // head
  k_head<<<NG, 256, 0, stream>>>(g, Wl2, bl2, Wl3, bl3, Wl, bl, out);
}